// Round 12
// baseline (138.528 us; speedup 1.0000x reference)
//
#include <hip/hip_runtime.h>
#include <hip/hip_bf16.h>
#include <stdint.h>

typedef __attribute__((ext_vector_type(8))) __bf16 bf16x8;
typedef __attribute__((ext_vector_type(4))) float f32x4;
typedef __attribute__((ext_vector_type(2))) float f32x2;

#define N_PTS 1600
#define HD    64

// ---- ws layout (bytes), total 9.22 MB (proven safe R4-R11).
// [0, 6553600) time-multiplexed: Xc/WT/bias/VhT (dead after k_smooth) -> Opart.
#define OFF_XC   0u          //  819200 : [1600][256] bf16 canonical x
#define OFF_WT   819200u     //  393216 : 3 x [256 o][256 k] bf16 transposed W
#define OFF_BIAS 1212416u    //    1536 : 3 x 256 bf16
#define OFF_VHT  1213952u    //  819200 : [4][64][1600] raw V^T
#define OFF_OP   0u          // 6553600 : [2 z][4 kg][1600 n][256 o] bf16 O partials
#define OFF_LP   6553600u    //  204800 : [2 z][4 kg][4 hq][1600 n] f32 L partials
#define OFF_QH   6758400u    //  819200 : [4][1600][64] bf16 Q (pre-scaled by log2e/16)
#define OFF_KH   7577600u    //  819200 : [4][1600][64] bf16 K
#define OFF_VST  8396800u    //  819200 : [4][64][1600] bf16 smoothed V^T

__device__ __forceinline__ float bf2f(ushort h) {
  union { uint32_t u; float f; } v; v.u = ((uint32_t)h) << 16; return v.f;
}
__device__ __forceinline__ ushort f2bf(float f) {
  union { float f; uint32_t u; } v; v.f = f;
  uint32_t u = v.u;
  return (ushort)((u + 0x7FFFu + ((u >> 16) & 1u)) >> 16);
}
__device__ __forceinline__ uint32_t pk2(float a, float b) {
  union { __hip_bfloat162 h; uint32_t u; } cv;
  cv.h = __float22bfloat162_rn(make_float2(a, b));
  return cv.u;
}

// block-uniform dtype detect: sample x's first 4 KB; f32 buffers decode as huge/NaN bf16
__device__ __forceinline__ int detect_f32(const ushort* xu, int* shflag) {
  int t = threadIdx.x & 255;
  if (t == 0) *shflag = 0;
  __syncthreads();
  int local = 0;
#pragma unroll
  for (int i = 0; i < 4; ++i) {
    float v = bf2f(xu[(t * 4 + i) * 2]);
    if (!(fabsf(v) < 1e4f)) local = 1;
  }
  if (local) atomicOr(shflag, 1);
  __syncthreads();
  return *shflag;
}

// ---- prep: convert x/biases to bf16, transpose+convert the 3 weight matrices ----
__global__ void k_prep(const void* __restrict__ x, const void* __restrict__ Wq,
                       const void* __restrict__ bq, const void* __restrict__ Wk,
                       const void* __restrict__ bk, const void* __restrict__ Wv,
                       const void* __restrict__ bv, char* __restrict__ ws) {
  __shared__ int shflag;
  __shared__ ushort tileb[32][33];
  int isf32 = detect_f32((const ushort*)x, &shflag);
  int b = blockIdx.x, t = threadIdx.x;

  if (b < 400) {                       // x: 409600 elems, 1024/block
    ushort4 o;
    if (isf32) {
      float4 f = ((const float4*)x)[b * 256 + t];
      o.x = f2bf(f.x); o.y = f2bf(f.y); o.z = f2bf(f.z); o.w = f2bf(f.w);
    } else {
      o = ((const ushort4*)x)[b * 256 + t];
    }
    ((ushort4*)(ws + OFF_XC))[b * 256 + t] = o;
  } else if (b < 592) {                // W transpose: 64 32x32 tiles per z
    int w = b - 400, z = w >> 6, tile = w & 63;
    const void* W = (z == 0) ? Wq : ((z == 1) ? Wk : Wv);
    int o0 = (tile & 7) * 32, k0 = (tile >> 3) * 32;
    int tx = t & 31, ty = t >> 5;
#pragma unroll
    for (int i = 0; i < 32; i += 8) {
      int kk = (k0 + ty + i) * 256 + o0 + tx;
      tileb[ty + i][tx] = isf32 ? f2bf(((const float*)W)[kk]) : ((const ushort*)W)[kk];
    }
    __syncthreads();
    ushort* WT = (ushort*)(ws + OFF_WT) + z * 65536;
#pragma unroll
    for (int i = 0; i < 32; i += 8)
      WT[(o0 + ty + i) * 256 + k0 + tx] = tileb[tx][ty + i];
  } else {                             // biases
    ushort* bb = (ushort*)(ws + OFF_BIAS);
#pragma unroll
    for (int z = 0; z < 3; ++z) {
      const void* B = (z == 0) ? bq : ((z == 1) ? bk : bv);
      bb[z * 256 + t] = isf32 ? f2bf(((const float*)B)[t]) : ((const ushort*)B)[t];
    }
  }
}

// -------- projections: 4 waves/block = 4 heads. Q pre-scaled log2e/16; V transposed --------
__launch_bounds__(256)
__global__ void k_proj(const ushort* __restrict__ X, const ushort* __restrict__ WT,
                       const ushort* __restrict__ bias3,
                       ushort* __restrict__ Qh, ushort* __restrict__ Kh, ushort* __restrict__ VhT) {
  int z = blockIdx.z;
  const ushort* WTz = WT + z * 65536;
  const ushort* bias = bias3 + z * 256;
  int n0 = blockIdx.x * 16;
  int head = threadIdx.x >> 6;
  int lane = threadIdx.x & 63;
  int c = lane & 15, quad = lane >> 4;

  f32x4 acc[4];
#pragma unroll
  for (int i = 0; i < 4; ++i) acc[i] = (f32x4){0.f, 0.f, 0.f, 0.f};

  const ushort* xrow = X + (n0 + c) * 256;
#pragma unroll
  for (int kt = 0; kt < 8; ++kt) {
    bf16x8 a = *(const bf16x8*)(xrow + kt * 32 + quad * 8);
#pragma unroll
    for (int os = 0; os < 4; ++os) {
      bf16x8 bfr = *(const bf16x8*)(WTz + (head * 64 + os * 16 + c) * 256 + kt * 32 + quad * 8);
      acc[os] = __builtin_amdgcn_mfma_f32_16x16x32_bf16(a, bfr, acc[os], 0, 0, 0);
    }
  }
  if (z == 2) {
#pragma unroll
    for (int os = 0; os < 4; ++os) {
      float bval = bf2f(bias[head * 64 + os * 16 + c]);
      ushort4 v;
      v.x = f2bf(acc[os][0] + bval); v.y = f2bf(acc[os][1] + bval);
      v.z = f2bf(acc[os][2] + bval); v.w = f2bf(acc[os][3] + bval);
      *(ushort4*)(VhT + (head * 64 + os * 16 + c) * N_PTS + n0 + quad * 4) = v;
    }
  } else {
    // fold 1/sqrt(256) AND log2(e) into Q so the softmax uses exp2
    float scale = (z == 0) ? 0.0625f * 1.44269504088896f : 1.0f;
    ushort* out = (z == 0) ? Qh : Kh;
#pragma unroll
    for (int os = 0; os < 4; ++os) {
      float bval = bf2f(bias[head * 64 + os * 16 + c]);
#pragma unroll
      for (int r = 0; r < 4; ++r)
        out[head * (N_PTS * HD) + (n0 + quad * 4 + r) * HD + os * 16 + c] =
            f2bf((acc[os][r] + bval) * scale);
    }
  }
}

// --- smooth along m (coalesced): VsT[g][d][m] = sum_{sh in {-4,-2,0,2,4}} VhT[g][d][(m+sh)%1600]
__global__ void k_smooth(const ushort* __restrict__ VhT, ushort* __restrict__ VsT) {
  int idx = blockIdx.x * 256 + threadIdx.x;
  int m = idx % N_PTS;
  int base = idx - m;
  float s = 0.f;
#pragma unroll
  for (int sh = -4; sh <= 4; sh += 2)
    s += bf2f(VhT[base + ((m + sh + N_PTS) % N_PTS)]);
  VsT[idx] = f2bf(s);
}

// exp2 + pack 8 scores into the 16x16x32 PV A-fragment (permuted-key trick, validated R9)
__device__ __forceinline__ bf16x8 pack_p8(const f32x4& s0, const f32x4& s1, float& lp) {
  float e0 = exp2f(s0[0]), e1 = exp2f(s0[1]), e2 = exp2f(s0[2]), e3 = exp2f(s0[3]);
  float e4 = exp2f(s1[0]), e5 = exp2f(s1[1]), e6 = exp2f(s1[2]), e7 = exp2f(s1[3]);
  lp += ((e0 + e1) + (e2 + e3)) + ((e4 + e5) + (e6 + e7));
  union { uint32_t u[4]; bf16x8 v; } r;
  r.u[0] = pk2(e0, e1); r.u[1] = pk2(e2, e3);
  r.u[2] = pk2(e4, e5); r.u[3] = pk2(e6, e7);
  return r.v;
}

// ---- attention: grid (100 qt, 8 = hp*4+kg, 2 z). 8 waves = 8 key-subsplits (512 thr).
// R10 structure with a SAFE register bound: (512,2) caps at 256 VGPR (need ~68) -> no spill.
__launch_bounds__(512, 2)
__global__ void k_attn(const ushort* __restrict__ Qh, const ushort* __restrict__ Kh,
                       const ushort* __restrict__ VsT, ushort* __restrict__ Opart,
                       float* __restrict__ Lpart) {
  int qt = blockIdx.x;
  int yy = blockIdx.y;           // hp*4 + kg
  int z  = blockIdx.z;           // key half
  int hp = yy >> 2, kg = yy & 3;
  int vg = (2 * hp - kg + 8) & 3;
  int tid = threadIdx.x, sp = tid >> 6, lane = tid & 63;
  int c = lane & 15, quad = lane >> 4;
  int n0 = qt * 16;
  int perm = ((c >> 2) << 3) + (c & 3);   // key permutation for QK A-frag

  __shared__ float obuf[8][16][68];   // [sp][q][d] f32 partials (epilogue only)
  __shared__ float lbuf[8][16];

  const ushort* q0row = Qh + ((hp    ) * N_PTS + n0 + c) * HD;
  const ushort* q1row = Qh + ((hp + 2) * N_PTS + n0 + c) * HD;
  bf16x8 qa00 = *(const bf16x8*)(q0row + quad * 8);
  bf16x8 qa01 = *(const bf16x8*)(q0row + 32 + quad * 8);
  bf16x8 qa10 = *(const bf16x8*)(q1row + quad * 8);
  bf16x8 qa11 = *(const bf16x8*)(q1row + 32 + quad * 8);

  f32x4 oacc0[4], oacc1[4];
#pragma unroll
  for (int i = 0; i < 4; ++i) {
    oacc0[i] = (f32x4){0.f, 0.f, 0.f, 0.f};
    oacc1[i] = (f32x4){0.f, 0.f, 0.f, 0.f};
  }
  float lp0 = 0.f, lp1 = 0.f;

  // 25 tiles per z-half, split 4/3/3/3/3/3/3/3 across the 8 sp waves
  int off = (sp == 0) ? 0 : 1 + sp * 3;
  int iters = (sp == 0) ? 4 : 3;
  int kbase = z * 800 + off * 32;
  const f32x4 z4 = (f32x4){0.f, 0.f, 0.f, 0.f};

  for (int it = 0; it < iters; ++it) {
    int key0 = kbase + it * 32;
    const ushort* kr = Kh + (kg * N_PTS + key0 + perm) * HD;
    bf16x8 ka0 = *(const bf16x8*)(kr + quad * 8);            // keys quad*8+r, dims 0..31
    bf16x8 ka1 = *(const bf16x8*)(kr + 32 + quad * 8);       // dims 32..63
    bf16x8 kb0 = *(const bf16x8*)(kr + 4 * HD + quad * 8);   // keys quad*8+4+r
    bf16x8 kb1 = *(const bf16x8*)(kr + 4 * HD + 32 + quad * 8);
    bf16x8 vb[4];
#pragma unroll
    for (int ds = 0; ds < 4; ++ds)
      vb[ds] = *(const bf16x8*)(VsT + (vg * HD + ds * 16 + c) * N_PTS + key0 + quad * 8);

    // head 0
    f32x4 s0 = __builtin_amdgcn_mfma_f32_16x16x32_bf16(ka0, qa00, z4, 0, 0, 0);
    s0 = __builtin_amdgcn_mfma_f32_16x16x32_bf16(ka1, qa01, s0, 0, 0, 0);
    f32x4 s1 = __builtin_amdgcn_mfma_f32_16x16x32_bf16(kb0, qa00, z4, 0, 0, 0);
    s1 = __builtin_amdgcn_mfma_f32_16x16x32_bf16(kb1, qa01, s1, 0, 0, 0);
    bf16x8 pa = pack_p8(s0, s1, lp0);
#pragma unroll
    for (int ds = 0; ds < 4; ++ds)
      oacc0[ds] = __builtin_amdgcn_mfma_f32_16x16x32_bf16(pa, vb[ds], oacc0[ds], 0, 0, 0);

    // head 1 (hp+2): same K and V fragments
    s0 = __builtin_amdgcn_mfma_f32_16x16x32_bf16(ka0, qa10, z4, 0, 0, 0);
    s0 = __builtin_amdgcn_mfma_f32_16x16x32_bf16(ka1, qa11, s0, 0, 0, 0);
    s1 = __builtin_amdgcn_mfma_f32_16x16x32_bf16(kb0, qa10, z4, 0, 0, 0);
    s1 = __builtin_amdgcn_mfma_f32_16x16x32_bf16(kb1, qa11, s1, 0, 0, 0);
    bf16x8 pa1 = pack_p8(s0, s1, lp1);
#pragma unroll
    for (int ds = 0; ds < 4; ++ds)
      oacc1[ds] = __builtin_amdgcn_mfma_f32_16x16x32_bf16(pa1, vb[ds], oacc1[ds], 0, 0, 0);
  }

  // per-wave L: lanes c, c+16, c+32, c+48 hold disjoint-key partials for q=c
  lp0 += __shfl_xor(lp0, 16, 64); lp0 += __shfl_xor(lp0, 32, 64);
  lp1 += __shfl_xor(lp1, 16, 64); lp1 += __shfl_xor(lp1, 32, 64);

  // O C-layout: oaccX[ds] reg r = O[q=quad*4+r][d=ds*16+c]; reduce 8 sp in LDS
#pragma unroll
  for (int h = 0; h < 2; ++h) {
    __syncthreads();
    const f32x4* oa = h ? oacc1 : oacc0;
#pragma unroll
    for (int ds = 0; ds < 4; ++ds)
#pragma unroll
      for (int r = 0; r < 4; ++r)
        obuf[sp][quad * 4 + r][ds * 16 + c] = oa[ds][r];
    if (quad == 0) lbuf[sp][c] = h ? lp1 : lp0;
    __syncthreads();

    int q = tid >> 5, d0 = (tid & 31) * 2;   // 512 threads: 16 q x 32 d-pairs
    f32x2 a = (f32x2){0.f, 0.f};
    float l = 0.f;
#pragma unroll
    for (int sp2 = 0; sp2 < 8; ++sp2) {
      a += *(const f32x2*)&obuf[sp2][q][d0];
      l += lbuf[sp2][q];
    }
    int hq = hp + 2 * h;
    *(uint32_t*)&Opart[(size_t)((z * 4 + kg) * N_PTS + n0 + q) * 256 + hq * 64 + d0] =
        pk2(a[0], a[1]);
    if ((tid & 31) == 0)
      Lpart[((z * 4 + kg) * 4 + hq) * N_PTS + n0 + q] = l;
  }
}

// ---- final: out = sum_kg w(kg,hq) * (sum_z O) / (sum_z L), cast per detected dtype ----
__global__ void k_out(const ushort* __restrict__ Opart, const float* __restrict__ Lpart,
                      const void* __restrict__ x, void* __restrict__ out) {
  __shared__ int shflag;
  int isf32 = detect_f32((const ushort*)x, &shflag);
  int idx = blockIdx.x * 256 + threadIdx.x;
  int n = idx >> 8, o = idx & 255, hq = o >> 6;
  float acc = 0.f;
#pragma unroll
  for (int kg = 0; kg < 4; ++kg) {
    float num = bf2f(Opart[(size_t)((0 + kg) * N_PTS + n) * 256 + o]) +
                bf2f(Opart[(size_t)((4 + kg) * N_PTS + n) * 256 + o]);
    float l = Lpart[((0 + kg) * 4 + hq) * N_PTS + n] +
              Lpart[((4 + kg) * 4 + hq) * N_PTS + n];
    float w = (kg == ((hq + 2) & 3)) ? 2.f : 1.f;
    acc += w * num / l;
  }
  if (isf32) ((float*)out)[idx] = acc;
  else       ((ushort*)out)[idx] = f2bf(acc);
}

extern "C" void kernel_launch(void* const* d_in, const int* in_sizes, int n_in,
                              void* d_out, int out_size, void* d_ws, size_t ws_size,
                              hipStream_t stream) {
  char* ws = (char*)d_ws;
  ushort* Xc    = (ushort*)(ws + OFF_XC);
  ushort* WT    = (ushort*)(ws + OFF_WT);
  ushort* bias3 = (ushort*)(ws + OFF_BIAS);
  ushort* VhT   = (ushort*)(ws + OFF_VHT);
  ushort* Opart = (ushort*)(ws + OFF_OP);
  float*  Lpart = (float*)(ws + OFF_LP);
  ushort* Qh    = (ushort*)(ws + OFF_QH);
  ushort* Kh    = (ushort*)(ws + OFF_KH);
  ushort* VsT   = (ushort*)(ws + OFF_VST);

  k_prep<<<593, 256, 0, stream>>>(d_in[0], d_in[1], d_in[2], d_in[3],
                                  d_in[4], d_in[5], d_in[6], ws);
  k_proj<<<dim3(100, 1, 3), 256, 0, stream>>>(Xc, WT, bias3, Qh, Kh, VhT);
  k_smooth<<<1600, 256, 0, stream>>>(VhT, VsT);
  k_attn<<<dim3(100, 8, 2), 512, 0, stream>>>(Qh, Kh, VsT, Opart, Lpart);
  k_out<<<1600, 256, 0, stream>>>(Opart, Lpart, d_in[0], d_out);
}

// Round 13
// 112.626 us; speedup vs baseline: 1.2300x; 1.2300x over previous
//
#include <hip/hip_runtime.h>
#include <hip/hip_bf16.h>
#include <stdint.h>

typedef __attribute__((ext_vector_type(8))) __bf16 bf16x8;
typedef __attribute__((ext_vector_type(4))) float f32x4;

#define N_PTS 1600
#define HD    64

// ---- ws layout (bytes), high-water 9610752 < 9.83 MB proven safe (R4-R12).
// Time-multiplexed: XC/WT/BIAS/VHT die after proj/smooth -> KF/VF reuse them;
// KH/VST die after k_frag -> OP/LP reuse that region.
#define OFF_XC   0u          //  819200 : [1600][256] bf16 canonical x (dead after proj)
#define OFF_WT   819200u     //  393216 : 3 x [256][256] bf16 W^T (dead after proj)
#define OFF_BIAS 1212416u    //    1536 : 3 x 256 bf16 (dead after proj)
#define OFF_VHT  1213952u    //  819200 : [4][64][1600] raw V^T (dead after smooth)
#define OFF_QH   2033152u    //  819200 : [4][1600][64] bf16 Q (live through attn)
#define OFF_KH   2852352u    //  819200 : [4][1600][64] bf16 K (dead after frag)
#define OFF_VST  3671552u    //  819200 : [4][64][1600] bf16 smoothed V^T (dead after frag)
#define OFF_KF   0u          //  819200 : fragment-major K  [kg][50 t][4 ch][64 lane][8]
#define OFF_VF   819200u     //  819200 : fragment-major Vs [vg][50 t][4 ds][64 lane][8]
#define OFF_OP   2852352u    // 6553600 : [2 z][4 kg][1600 n][256 o] bf16 O partials
#define OFF_LP   9405952u    //  204800 : [2 z][4 kg][4 hq][1600 n] f32 L partials

__device__ __forceinline__ float bf2f(ushort h) {
  union { uint32_t u; float f; } v; v.u = ((uint32_t)h) << 16; return v.f;
}
__device__ __forceinline__ ushort f2bf(float f) {
  union { float f; uint32_t u; } v; v.f = f;
  uint32_t u = v.u;
  return (ushort)((u + 0x7FFFu + ((u >> 16) & 1u)) >> 16);
}
__device__ __forceinline__ uint32_t pk2(float a, float b) {
  union { __hip_bfloat162 h; uint32_t u; } cv;
  cv.h = __float22bfloat162_rn(make_float2(a, b));
  return cv.u;
}

// block-uniform dtype detect: sample x's first 4 KB; f32 buffers decode as huge/NaN bf16
__device__ __forceinline__ int detect_f32(const ushort* xu, int* shflag) {
  int t = threadIdx.x & 255;
  if (t == 0) *shflag = 0;
  __syncthreads();
  int local = 0;
#pragma unroll
  for (int i = 0; i < 4; ++i) {
    float v = bf2f(xu[(t * 4 + i) * 2]);
    if (!(fabsf(v) < 1e4f)) local = 1;
  }
  if (local) atomicOr(shflag, 1);
  __syncthreads();
  return *shflag;
}

// ---- prep: convert x/biases to bf16, transpose+convert the 3 weight matrices ----
__global__ void k_prep(const void* __restrict__ x, const void* __restrict__ Wq,
                       const void* __restrict__ bq, const void* __restrict__ Wk,
                       const void* __restrict__ bk, const void* __restrict__ Wv,
                       const void* __restrict__ bv, char* __restrict__ ws) {
  __shared__ int shflag;
  __shared__ ushort tileb[32][33];
  int isf32 = detect_f32((const ushort*)x, &shflag);
  int b = blockIdx.x, t = threadIdx.x;

  if (b < 400) {                       // x: 409600 elems, 1024/block
    ushort4 o;
    if (isf32) {
      float4 f = ((const float4*)x)[b * 256 + t];
      o.x = f2bf(f.x); o.y = f2bf(f.y); o.z = f2bf(f.z); o.w = f2bf(f.w);
    } else {
      o = ((const ushort4*)x)[b * 256 + t];
    }
    ((ushort4*)(ws + OFF_XC))[b * 256 + t] = o;
  } else if (b < 592) {                // W transpose: 64 32x32 tiles per z
    int w = b - 400, z = w >> 6, tile = w & 63;
    const void* W = (z == 0) ? Wq : ((z == 1) ? Wk : Wv);
    int o0 = (tile & 7) * 32, k0 = (tile >> 3) * 32;
    int tx = t & 31, ty = t >> 5;
#pragma unroll
    for (int i = 0; i < 32; i += 8) {
      int kk = (k0 + ty + i) * 256 + o0 + tx;
      tileb[ty + i][tx] = isf32 ? f2bf(((const float*)W)[kk]) : ((const ushort*)W)[kk];
    }
    __syncthreads();
    ushort* WT = (ushort*)(ws + OFF_WT) + z * 65536;
#pragma unroll
    for (int i = 0; i < 32; i += 8)
      WT[(o0 + ty + i) * 256 + k0 + tx] = tileb[tx][ty + i];
  } else {                             // biases
    ushort* bb = (ushort*)(ws + OFF_BIAS);
#pragma unroll
    for (int z = 0; z < 3; ++z) {
      const void* B = (z == 0) ? bq : ((z == 1) ? bk : bv);
      bb[z * 256 + t] = isf32 ? f2bf(((const float*)B)[t]) : ((const ushort*)B)[t];
    }
  }
}

// -------- projections: 4 waves/block = 4 heads. Q pre-scaled log2e/16; V transposed --------
__launch_bounds__(256)
__global__ void k_proj(const ushort* __restrict__ X, const ushort* __restrict__ WT,
                       const ushort* __restrict__ bias3,
                       ushort* __restrict__ Qh, ushort* __restrict__ Kh, ushort* __restrict__ VhT) {
  int z = blockIdx.z;
  const ushort* WTz = WT + z * 65536;
  const ushort* bias = bias3 + z * 256;
  int n0 = blockIdx.x * 16;
  int head = threadIdx.x >> 6;
  int lane = threadIdx.x & 63;
  int c = lane & 15, quad = lane >> 4;

  f32x4 acc[4];
#pragma unroll
  for (int i = 0; i < 4; ++i) acc[i] = (f32x4){0.f, 0.f, 0.f, 0.f};

  const ushort* xrow = X + (n0 + c) * 256;
#pragma unroll
  for (int kt = 0; kt < 8; ++kt) {
    bf16x8 a = *(const bf16x8*)(xrow + kt * 32 + quad * 8);
#pragma unroll
    for (int os = 0; os < 4; ++os) {
      bf16x8 bfr = *(const bf16x8*)(WTz + (head * 64 + os * 16 + c) * 256 + kt * 32 + quad * 8);
      acc[os] = __builtin_amdgcn_mfma_f32_16x16x32_bf16(a, bfr, acc[os], 0, 0, 0);
    }
  }
  if (z == 2) {
#pragma unroll
    for (int os = 0; os < 4; ++os) {
      float bval = bf2f(bias[head * 64 + os * 16 + c]);
      ushort4 v;
      v.x = f2bf(acc[os][0] + bval); v.y = f2bf(acc[os][1] + bval);
      v.z = f2bf(acc[os][2] + bval); v.w = f2bf(acc[os][3] + bval);
      *(ushort4*)(VhT + (head * 64 + os * 16 + c) * N_PTS + n0 + quad * 4) = v;
    }
  } else {
    // fold 1/sqrt(256) AND log2(e) into Q so the softmax uses exp2
    float scale = (z == 0) ? 0.0625f * 1.44269504088896f : 1.0f;
    ushort* out = (z == 0) ? Qh : Kh;
#pragma unroll
    for (int os = 0; os < 4; ++os) {
      float bval = bf2f(bias[head * 64 + os * 16 + c]);
#pragma unroll
      for (int r = 0; r < 4; ++r)
        out[head * (N_PTS * HD) + (n0 + quad * 4 + r) * HD + os * 16 + c] =
            f2bf((acc[os][r] + bval) * scale);
    }
  }
}

// --- smooth along m (coalesced): VsT[g][d][m] = sum_{sh in {-4,-2,0,2,4}} VhT[g][d][(m+sh)%1600]
__global__ void k_smooth(const ushort* __restrict__ VhT, ushort* __restrict__ VsT) {
  int idx = blockIdx.x * 256 + threadIdx.x;
  int m = idx % N_PTS;
  int base = idx - m;
  float s = 0.f;
#pragma unroll
  for (int sh = -4; sh <= 4; sh += 2)
    s += bf2f(VhT[base + ((m + sh + N_PTS) % N_PTS)]);
  VsT[idx] = f2bf(s);
}

// ---- fragment-layout remap: make every k_attn load a coalesced lane*16B stream.
// Kf chunk (kg,t,ch,lane): ch0/1 = keys t*32+perm(c), dims 0-31/32-63;
//                          ch2/3 = keys +4. Vf chunk (vg,t,ds,lane) = Vs[d=ds*16+c][t*32+quad*8..].
__global__ void k_frag(const ushort* __restrict__ Kh, const ushort* __restrict__ VsT,
                       ushort* __restrict__ Kf, ushort* __restrict__ Vf) {
  int q = blockIdx.x * 256 + threadIdx.x;   // 102400 threads, one 16B chunk each
  int isV = q >= 51200;
  int idx = isV ? q - 51200 : q;
  int lane = idx & 63, ch = (idx >> 6) & 3;
  int rest = idx >> 8;
  int t = rest % 50, g = rest / 50;         // g = kg or vg
  int c = lane & 15, quad = lane >> 4;
  bf16x8 v;
  if (!isV) {
    int perm = ((c >> 2) << 3) + (c & 3);
    int key = t * 32 + perm + ((ch >> 1) << 2);
    int d0 = (ch & 1) * 32 + quad * 8;
    v = *(const bf16x8*)(Kh + (size_t)(g * N_PTS + key) * HD + d0);
    *(bf16x8*)(Kf + (size_t)idx * 8) = v;
  } else {
    int d = ch * 16 + c;
    int m0 = t * 32 + quad * 8;
    v = *(const bf16x8*)(VsT + (size_t)(g * HD + d) * N_PTS + m0);
    *(bf16x8*)(Vf + (size_t)idx * 8) = v;
  }
}

// exp2 + pack 8 scores into the 16x16x32 PV A-fragment (permuted-key trick, validated R9)
__device__ __forceinline__ bf16x8 pack_p8(const f32x4& s0, const f32x4& s1, float& lp) {
  float e0 = exp2f(s0[0]), e1 = exp2f(s0[1]), e2 = exp2f(s0[2]), e3 = exp2f(s0[3]);
  float e4 = exp2f(s1[0]), e5 = exp2f(s1[1]), e6 = exp2f(s1[2]), e7 = exp2f(s1[3]);
  lp += ((e0 + e1) + (e2 + e3)) + ((e4 + e5) + (e6 + e7));
  union { uint32_t u[4]; bf16x8 v; } r;
  r.u[0] = pk2(e0, e1); r.u[1] = pk2(e2, e3);
  r.u[2] = pk2(e4, e5); r.u[3] = pk2(e6, e7);
  return r.v;
}

// ---- attention: grid (100 qt, 8 = hp*4+kg, 2 z). 4 waves = 4 key-subsplits.
// ALL loads fragment-major + coalesced (base + t*4096 + lane*16). No LDS in loop.
__launch_bounds__(256, 4)
__global__ void k_attn(const ushort* __restrict__ Qh, const ushort* __restrict__ Kf,
                       const ushort* __restrict__ Vf, ushort* __restrict__ Opart,
                       float* __restrict__ Lpart) {
  int qt = blockIdx.x;
  int yy = blockIdx.y;           // hp*4 + kg
  int z  = blockIdx.z;           // key half
  int hp = yy >> 2, kg = yy & 3;
  int vg = (2 * hp - kg + 8) & 3;
  int tid = threadIdx.x, sp = tid >> 6, lane = tid & 63;
  int c = lane & 15, quad = lane >> 4;
  int n0 = qt * 16;

  __shared__ float obuf[4][16][68];   // [sp][q][d] f32 partials (epilogue only)
  __shared__ float lbuf[4][16];

  const ushort* q0row = Qh + ((hp    ) * N_PTS + n0 + c) * HD;
  const ushort* q1row = Qh + ((hp + 2) * N_PTS + n0 + c) * HD;
  bf16x8 qa00 = *(const bf16x8*)(q0row + quad * 8);
  bf16x8 qa01 = *(const bf16x8*)(q0row + 32 + quad * 8);
  bf16x8 qa10 = *(const bf16x8*)(q1row + quad * 8);
  bf16x8 qa11 = *(const bf16x8*)(q1row + 32 + quad * 8);

  f32x4 oacc0[4], oacc1[4];
#pragma unroll
  for (int i = 0; i < 4; ++i) {
    oacc0[i] = (f32x4){0.f, 0.f, 0.f, 0.f};
    oacc1[i] = (f32x4){0.f, 0.f, 0.f, 0.f};
  }
  float lp0 = 0.f, lp1 = 0.f;

  // 25 tiles per z-half, split 7/6/6/6 across the 4 sp waves
  int off = (sp == 0) ? 0 : (sp == 1) ? 7 : (sp == 2) ? 13 : 19;
  int iters = (sp == 0) ? 7 : 6;
  int t0 = z * 25 + off;
  const f32x4 z4 = (f32x4){0.f, 0.f, 0.f, 0.f};

  const char* kfp = (const char*)Kf + (size_t)(kg * 50 + t0) * 4096 + lane * 16;
  const char* vfp = (const char*)Vf + (size_t)(vg * 50 + t0) * 4096 + lane * 16;

  for (int it = 0; it < iters; ++it) {
    const char* kt = kfp + it * 4096;
    const char* vt = vfp + it * 4096;
    bf16x8 ka0 = *(const bf16x8*)(kt);
    bf16x8 ka1 = *(const bf16x8*)(kt + 1024);
    bf16x8 kb0 = *(const bf16x8*)(kt + 2048);
    bf16x8 kb1 = *(const bf16x8*)(kt + 3072);
    bf16x8 vb[4];
#pragma unroll
    for (int ds = 0; ds < 4; ++ds)
      vb[ds] = *(const bf16x8*)(vt + ds * 1024);

    // head 0
    f32x4 s0 = __builtin_amdgcn_mfma_f32_16x16x32_bf16(ka0, qa00, z4, 0, 0, 0);
    s0 = __builtin_amdgcn_mfma_f32_16x16x32_bf16(ka1, qa01, s0, 0, 0, 0);
    f32x4 s1 = __builtin_amdgcn_mfma_f32_16x16x32_bf16(kb0, qa00, z4, 0, 0, 0);
    s1 = __builtin_amdgcn_mfma_f32_16x16x32_bf16(kb1, qa01, s1, 0, 0, 0);
    bf16x8 pa = pack_p8(s0, s1, lp0);
#pragma unroll
    for (int ds = 0; ds < 4; ++ds)
      oacc0[ds] = __builtin_amdgcn_mfma_f32_16x16x32_bf16(pa, vb[ds], oacc0[ds], 0, 0, 0);

    // head 1 (hp+2): same K and V fragments
    s0 = __builtin_amdgcn_mfma_f32_16x16x32_bf16(ka0, qa10, z4, 0, 0, 0);
    s0 = __builtin_amdgcn_mfma_f32_16x16x32_bf16(ka1, qa11, s0, 0, 0, 0);
    s1 = __builtin_amdgcn_mfma_f32_16x16x32_bf16(kb0, qa10, z4, 0, 0, 0);
    s1 = __builtin_amdgcn_mfma_f32_16x16x32_bf16(kb1, qa11, s1, 0, 0, 0);
    bf16x8 pa1 = pack_p8(s0, s1, lp1);
#pragma unroll
    for (int ds = 0; ds < 4; ++ds)
      oacc1[ds] = __builtin_amdgcn_mfma_f32_16x16x32_bf16(pa1, vb[ds], oacc1[ds], 0, 0, 0);
  }

  // per-wave L: lanes c, c+16, c+32, c+48 hold disjoint-key partials for q=c
  lp0 += __shfl_xor(lp0, 16, 64); lp0 += __shfl_xor(lp0, 32, 64);
  lp1 += __shfl_xor(lp1, 16, 64); lp1 += __shfl_xor(lp1, 32, 64);

  // O C-layout: oaccX[ds] reg r = O[q=quad*4+r][d=ds*16+c]; reduce sp in LDS
#pragma unroll
  for (int h = 0; h < 2; ++h) {
    __syncthreads();
    const f32x4* oa = h ? oacc1 : oacc0;
#pragma unroll
    for (int ds = 0; ds < 4; ++ds)
#pragma unroll
      for (int r = 0; r < 4; ++r)
        obuf[sp][quad * 4 + r][ds * 16 + c] = oa[ds][r];
    if (quad == 0) lbuf[sp][c] = h ? lp1 : lp0;
    __syncthreads();

    int q = tid >> 4, d0 = (tid & 15) * 4;
    f32x4 a = *(const f32x4*)&obuf[0][q][d0];
    a += *(const f32x4*)&obuf[1][q][d0];
    a += *(const f32x4*)&obuf[2][q][d0];
    a += *(const f32x4*)&obuf[3][q][d0];
    float l = lbuf[0][q] + lbuf[1][q] + lbuf[2][q] + lbuf[3][q];
    int hq = hp + 2 * h;
    union { uint32_t u[2]; } wv;
    wv.u[0] = pk2(a[0], a[1]);
    wv.u[1] = pk2(a[2], a[3]);
    *(uint2*)&Opart[(size_t)((z * 4 + kg) * N_PTS + n0 + q) * 256 + hq * 64 + d0] =
        *(uint2*)wv.u;
    if ((tid & 15) == 0)
      Lpart[((z * 4 + kg) * 4 + hq) * N_PTS + n0 + q] = l;
  }
}

// ---- final: out = sum_kg w(kg,hq) * (sum_z O) / (sum_z L), cast per detected dtype ----
__global__ void k_out(const ushort* __restrict__ Opart, const float* __restrict__ Lpart,
                      const void* __restrict__ x, void* __restrict__ out) {
  __shared__ int shflag;
  int isf32 = detect_f32((const ushort*)x, &shflag);
  int idx = blockIdx.x * 256 + threadIdx.x;
  int n = idx >> 8, o = idx & 255, hq = o >> 6;
  float acc = 0.f;
#pragma unroll
  for (int kg = 0; kg < 4; ++kg) {
    float num = bf2f(Opart[(size_t)((0 + kg) * N_PTS + n) * 256 + o]) +
                bf2f(Opart[(size_t)((4 + kg) * N_PTS + n) * 256 + o]);
    float l = Lpart[((0 + kg) * 4 + hq) * N_PTS + n] +
              Lpart[((4 + kg) * 4 + hq) * N_PTS + n];
    float w = (kg == ((hq + 2) & 3)) ? 2.f : 1.f;
    acc += w * num / l;
  }
  if (isf32) ((float*)out)[idx] = acc;
  else       ((ushort*)out)[idx] = f2bf(acc);
}

extern "C" void kernel_launch(void* const* d_in, const int* in_sizes, int n_in,
                              void* d_out, int out_size, void* d_ws, size_t ws_size,
                              hipStream_t stream) {
  char* ws = (char*)d_ws;
  ushort* Xc    = (ushort*)(ws + OFF_XC);
  ushort* WT    = (ushort*)(ws + OFF_WT);
  ushort* bias3 = (ushort*)(ws + OFF_BIAS);
  ushort* VhT   = (ushort*)(ws + OFF_VHT);
  ushort* Qh    = (ushort*)(ws + OFF_QH);
  ushort* Kh    = (ushort*)(ws + OFF_KH);
  ushort* VsT   = (ushort*)(ws + OFF_VST);
  ushort* Kf    = (ushort*)(ws + OFF_KF);
  ushort* Vf    = (ushort*)(ws + OFF_VF);
  ushort* Opart = (ushort*)(ws + OFF_OP);
  float*  Lpart = (float*)(ws + OFF_LP);

  k_prep<<<593, 256, 0, stream>>>(d_in[0], d_in[1], d_in[2], d_in[3],
                                  d_in[4], d_in[5], d_in[6], ws);
  k_proj<<<dim3(100, 1, 3), 256, 0, stream>>>(Xc, WT, bias3, Qh, Kh, VhT);
  k_smooth<<<1600, 256, 0, stream>>>(VhT, VsT);
  k_frag<<<400, 256, 0, stream>>>(Kh, VsT, Kf, Vf);
  k_attn<<<dim3(100, 8, 2), 256, 0, stream>>>(Qh, Kf, Vf, Opart, Lpart);
  k_out<<<1600, 256, 0, stream>>>(Opart, Lpart, d_in[0], d_out);
}

// Round 14
// 111.954 us; speedup vs baseline: 1.2374x; 1.0060x over previous
//
#include <hip/hip_runtime.h>
#include <hip/hip_bf16.h>
#include <stdint.h>

typedef __attribute__((ext_vector_type(8))) __bf16 bf16x8;
typedef __attribute__((ext_vector_type(4))) float f32x4;

#define N_PTS 1600
#define HD    64

// ---- ws layout (bytes). ws_size measured = 256 MiB (R13 fill counter), high-water ~10.4 MB.
// XC dead after proj -> KF reuses it. KH dead after frag -> OP reuses it. VF in fresh space
// (cannot overlap VhT: the fused frag kernel READS VhT while writing VF).
#define OFF_XC   0u          //  819200 : [1600][256] bf16 canonical x (dead after proj)
#define OFF_WT   819200u     //  393216 : 3 x [256][256] bf16 W^T (dead after proj)
#define OFF_BIAS 1212416u    //    1536 : 3 x 256 bf16 (dead after proj)
#define OFF_VHT  1213952u    //  819200 : [4][64][1600] raw V^T (dead after frag)
#define OFF_QH   2033152u    //  819200 : [4][1600][64] bf16 Q (live through attn)
#define OFF_KH   2852352u    //  819200 : [4][1600][64] bf16 K (dead after frag)
#define OFF_KF   0u          //  819200 : fragment-major K  [kg][50 t][4 ch][64 lane][8]
#define OFF_OP   2852352u    // 6553600 : [2 z][4 kg][1600 n][256 o] bf16 O partials
#define OFF_LP   9405952u    //  204800 : [2 z][4 kg][4 hq][1600 n] f32 L partials
#define OFF_VF   9610752u    //  819200 : fragment-major smoothed V [vg][50 t][4 ds][64 lane][8]

__device__ __forceinline__ float bf2f(ushort h) {
  union { uint32_t u; float f; } v; v.u = ((uint32_t)h) << 16; return v.f;
}
__device__ __forceinline__ ushort f2bf(float f) {
  union { float f; uint32_t u; } v; v.f = f;
  uint32_t u = v.u;
  return (ushort)((u + 0x7FFFu + ((u >> 16) & 1u)) >> 16);
}
__device__ __forceinline__ uint32_t pk2(float a, float b) {
  union { __hip_bfloat162 h; uint32_t u; } cv;
  cv.h = __float22bfloat162_rn(make_float2(a, b));
  return cv.u;
}

// block-uniform dtype detect: sample x's first 4 KB; f32 buffers decode as huge/NaN bf16
__device__ __forceinline__ int detect_f32(const ushort* xu, int* shflag) {
  int t = threadIdx.x & 255;
  if (t == 0) *shflag = 0;
  __syncthreads();
  int local = 0;
#pragma unroll
  for (int i = 0; i < 4; ++i) {
    float v = bf2f(xu[(t * 4 + i) * 2]);
    if (!(fabsf(v) < 1e4f)) local = 1;
  }
  if (local) atomicOr(shflag, 1);
  __syncthreads();
  return *shflag;
}

// ---- prep: convert x/biases to bf16, transpose+convert the 3 weight matrices ----
__global__ void k_prep(const void* __restrict__ x, const void* __restrict__ Wq,
                       const void* __restrict__ bq, const void* __restrict__ Wk,
                       const void* __restrict__ bk, const void* __restrict__ Wv,
                       const void* __restrict__ bv, char* __restrict__ ws) {
  __shared__ int shflag;
  __shared__ ushort tileb[32][33];
  int isf32 = detect_f32((const ushort*)x, &shflag);
  int b = blockIdx.x, t = threadIdx.x;

  if (b < 400) {                       // x: 409600 elems, 1024/block
    ushort4 o;
    if (isf32) {
      float4 f = ((const float4*)x)[b * 256 + t];
      o.x = f2bf(f.x); o.y = f2bf(f.y); o.z = f2bf(f.z); o.w = f2bf(f.w);
    } else {
      o = ((const ushort4*)x)[b * 256 + t];
    }
    ((ushort4*)(ws + OFF_XC))[b * 256 + t] = o;
  } else if (b < 592) {                // W transpose: 64 32x32 tiles per z
    int w = b - 400, z = w >> 6, tile = w & 63;
    const void* W = (z == 0) ? Wq : ((z == 1) ? Wk : Wv);
    int o0 = (tile & 7) * 32, k0 = (tile >> 3) * 32;
    int tx = t & 31, ty = t >> 5;
#pragma unroll
    for (int i = 0; i < 32; i += 8) {
      int kk = (k0 + ty + i) * 256 + o0 + tx;
      tileb[ty + i][tx] = isf32 ? f2bf(((const float*)W)[kk]) : ((const ushort*)W)[kk];
    }
    __syncthreads();
    ushort* WT = (ushort*)(ws + OFF_WT) + z * 65536;
#pragma unroll
    for (int i = 0; i < 32; i += 8)
      WT[(o0 + ty + i) * 256 + k0 + tx] = tileb[tx][ty + i];
  } else {                             // biases
    ushort* bb = (ushort*)(ws + OFF_BIAS);
#pragma unroll
    for (int z = 0; z < 3; ++z) {
      const void* B = (z == 0) ? bq : ((z == 1) ? bk : bv);
      bb[z * 256 + t] = isf32 ? f2bf(((const float*)B)[t]) : ((const ushort*)B)[t];
    }
  }
}

// -------- projections: 4 waves/block = 4 heads. Q pre-scaled log2e/16; V transposed --------
__launch_bounds__(256)
__global__ void k_proj(const ushort* __restrict__ X, const ushort* __restrict__ WT,
                       const ushort* __restrict__ bias3,
                       ushort* __restrict__ Qh, ushort* __restrict__ Kh, ushort* __restrict__ VhT) {
  int z = blockIdx.z;
  const ushort* WTz = WT + z * 65536;
  const ushort* bias = bias3 + z * 256;
  int n0 = blockIdx.x * 16;
  int head = threadIdx.x >> 6;
  int lane = threadIdx.x & 63;
  int c = lane & 15, quad = lane >> 4;

  f32x4 acc[4];
#pragma unroll
  for (int i = 0; i < 4; ++i) acc[i] = (f32x4){0.f, 0.f, 0.f, 0.f};

  const ushort* xrow = X + (n0 + c) * 256;
#pragma unroll
  for (int kt = 0; kt < 8; ++kt) {
    bf16x8 a = *(const bf16x8*)(xrow + kt * 32 + quad * 8);
#pragma unroll
    for (int os = 0; os < 4; ++os) {
      bf16x8 bfr = *(const bf16x8*)(WTz + (head * 64 + os * 16 + c) * 256 + kt * 32 + quad * 8);
      acc[os] = __builtin_amdgcn_mfma_f32_16x16x32_bf16(a, bfr, acc[os], 0, 0, 0);
    }
  }
  if (z == 2) {
#pragma unroll
    for (int os = 0; os < 4; ++os) {
      float bval = bf2f(bias[head * 64 + os * 16 + c]);
      ushort4 v;
      v.x = f2bf(acc[os][0] + bval); v.y = f2bf(acc[os][1] + bval);
      v.z = f2bf(acc[os][2] + bval); v.w = f2bf(acc[os][3] + bval);
      *(ushort4*)(VhT + (head * 64 + os * 16 + c) * N_PTS + n0 + quad * 4) = v;
    }
  } else {
    // fold 1/sqrt(256) AND log2(e) into Q so the softmax uses exp2
    float scale = (z == 0) ? 0.0625f * 1.44269504088896f : 1.0f;
    ushort* out = (z == 0) ? Qh : Kh;
#pragma unroll
    for (int os = 0; os < 4; ++os) {
      float bval = bf2f(bias[head * 64 + os * 16 + c]);
#pragma unroll
      for (int r = 0; r < 4; ++r)
        out[head * (N_PTS * HD) + (n0 + quad * 4 + r) * HD + os * 16 + c] =
            f2bf((acc[os][r] + bval) * scale);
    }
  }
}

// ---- fragment remap (K) + fused smooth+remap (V): every k_attn load becomes a
// coalesced lane*16B stream. Vs[g][d][m] = sum_{sh in {-4,-2,0,2,4}} VhT[g][d][(m+sh)%1600]
// computed inline from 3 overlapping bf16x8 loads (same rounding path as R13 -> bit-identical).
__global__ void k_frag(const ushort* __restrict__ Kh, const ushort* __restrict__ VhT,
                       ushort* __restrict__ Kf, ushort* __restrict__ Vf) {
  int q = blockIdx.x * 256 + threadIdx.x;   // 102400 threads, one 16B chunk each
  int isV = q >= 51200;
  int idx = isV ? q - 51200 : q;
  int lane = idx & 63, ch = (idx >> 6) & 3;
  int rest = idx >> 8;
  int t = rest % 50, g = rest / 50;         // g = kg or vg
  int c = lane & 15, quad = lane >> 4;
  if (!isV) {
    int perm = ((c >> 2) << 3) + (c & 3);
    int key = t * 32 + perm + ((ch >> 1) << 2);
    int d0 = (ch & 1) * 32 + quad * 8;
    bf16x8 v = *(const bf16x8*)(Kh + (size_t)(g * N_PTS + key) * HD + d0);
    *(bf16x8*)(Kf + (size_t)idx * 8) = v;
  } else {
    int d = ch * 16 + c;
    int m0 = t * 32 + quad * 8;
    const ushort* row = VhT + (size_t)(g * HD + d) * N_PTS;
    int mp = (m0 == 0) ? 1592 : m0 - 8;
    int mn = (m0 == 1592) ? 0 : m0 + 8;
    union { bf16x8 v[3]; ushort us[24]; } w;
    w.v[0] = *(const bf16x8*)(row + mp);
    w.v[1] = *(const bf16x8*)(row + m0);
    w.v[2] = *(const bf16x8*)(row + mn);
    union { ushort us[8]; bf16x8 v; } o;
#pragma unroll
    for (int j = 0; j < 8; ++j) {
      float s = bf2f(w.us[4 + j]) + bf2f(w.us[6 + j]) + bf2f(w.us[8 + j]) +
                bf2f(w.us[10 + j]) + bf2f(w.us[12 + j]);
      o.us[j] = f2bf(s);
    }
    *(bf16x8*)(Vf + (size_t)idx * 8) = o.v;
  }
}

// exp2 + pack 8 scores into the 16x16x32 PV A-fragment (permuted-key trick, validated R9)
__device__ __forceinline__ bf16x8 pack_p8(const f32x4& s0, const f32x4& s1, float& lp) {
  float e0 = exp2f(s0[0]), e1 = exp2f(s0[1]), e2 = exp2f(s0[2]), e3 = exp2f(s0[3]);
  float e4 = exp2f(s1[0]), e5 = exp2f(s1[1]), e6 = exp2f(s1[2]), e7 = exp2f(s1[3]);
  lp += ((e0 + e1) + (e2 + e3)) + ((e4 + e5) + (e6 + e7));
  union { uint32_t u[4]; bf16x8 v; } r;
  r.u[0] = pk2(e0, e1); r.u[1] = pk2(e2, e3);
  r.u[2] = pk2(e4, e5); r.u[3] = pk2(e6, e7);
  return r.v;
}

// ---- attention: grid (100 qt, 8 = hp*4+kg, 2 z). 4 waves = 4 key-subsplits.
// ALL loads fragment-major + coalesced (base + t*4096 + lane*16). No LDS in loop.
__launch_bounds__(256, 4)
__global__ void k_attn(const ushort* __restrict__ Qh, const ushort* __restrict__ Kf,
                       const ushort* __restrict__ Vf, ushort* __restrict__ Opart,
                       float* __restrict__ Lpart) {
  int qt = blockIdx.x;
  int yy = blockIdx.y;           // hp*4 + kg
  int z  = blockIdx.z;           // key half
  int hp = yy >> 2, kg = yy & 3;
  int vg = (2 * hp - kg + 8) & 3;
  int tid = threadIdx.x, sp = tid >> 6, lane = tid & 63;
  int c = lane & 15, quad = lane >> 4;
  int n0 = qt * 16;

  __shared__ float obuf[4][16][68];   // [sp][q][d] f32 partials (epilogue only)
  __shared__ float lbuf[4][16];

  const ushort* q0row = Qh + ((hp    ) * N_PTS + n0 + c) * HD;
  const ushort* q1row = Qh + ((hp + 2) * N_PTS + n0 + c) * HD;
  bf16x8 qa00 = *(const bf16x8*)(q0row + quad * 8);
  bf16x8 qa01 = *(const bf16x8*)(q0row + 32 + quad * 8);
  bf16x8 qa10 = *(const bf16x8*)(q1row + quad * 8);
  bf16x8 qa11 = *(const bf16x8*)(q1row + 32 + quad * 8);

  f32x4 oacc0[4], oacc1[4];
#pragma unroll
  for (int i = 0; i < 4; ++i) {
    oacc0[i] = (f32x4){0.f, 0.f, 0.f, 0.f};
    oacc1[i] = (f32x4){0.f, 0.f, 0.f, 0.f};
  }
  float lp0 = 0.f, lp1 = 0.f;

  // 25 tiles per z-half, split 7/6/6/6 across the 4 sp waves
  int off = (sp == 0) ? 0 : (sp == 1) ? 7 : (sp == 2) ? 13 : 19;
  int iters = (sp == 0) ? 7 : 6;
  int t0 = z * 25 + off;
  const f32x4 z4 = (f32x4){0.f, 0.f, 0.f, 0.f};

  const char* kfp = (const char*)Kf + (size_t)(kg * 50 + t0) * 4096 + lane * 16;
  const char* vfp = (const char*)Vf + (size_t)(vg * 50 + t0) * 4096 + lane * 16;

  for (int it = 0; it < iters; ++it) {
    const char* kt = kfp + it * 4096;
    const char* vt = vfp + it * 4096;
    bf16x8 ka0 = *(const bf16x8*)(kt);
    bf16x8 ka1 = *(const bf16x8*)(kt + 1024);
    bf16x8 kb0 = *(const bf16x8*)(kt + 2048);
    bf16x8 kb1 = *(const bf16x8*)(kt + 3072);
    bf16x8 vb[4];
#pragma unroll
    for (int ds = 0; ds < 4; ++ds)
      vb[ds] = *(const bf16x8*)(vt + ds * 1024);

    // head 0
    f32x4 s0 = __builtin_amdgcn_mfma_f32_16x16x32_bf16(ka0, qa00, z4, 0, 0, 0);
    s0 = __builtin_amdgcn_mfma_f32_16x16x32_bf16(ka1, qa01, s0, 0, 0, 0);
    f32x4 s1 = __builtin_amdgcn_mfma_f32_16x16x32_bf16(kb0, qa00, z4, 0, 0, 0);
    s1 = __builtin_amdgcn_mfma_f32_16x16x32_bf16(kb1, qa01, s1, 0, 0, 0);
    bf16x8 pa = pack_p8(s0, s1, lp0);
#pragma unroll
    for (int ds = 0; ds < 4; ++ds)
      oacc0[ds] = __builtin_amdgcn_mfma_f32_16x16x32_bf16(pa, vb[ds], oacc0[ds], 0, 0, 0);

    // head 1 (hp+2): same K and V fragments
    s0 = __builtin_amdgcn_mfma_f32_16x16x32_bf16(ka0, qa10, z4, 0, 0, 0);
    s0 = __builtin_amdgcn_mfma_f32_16x16x32_bf16(ka1, qa11, s0, 0, 0, 0);
    s1 = __builtin_amdgcn_mfma_f32_16x16x32_bf16(kb0, qa10, z4, 0, 0, 0);
    s1 = __builtin_amdgcn_mfma_f32_16x16x32_bf16(kb1, qa11, s1, 0, 0, 0);
    bf16x8 pa1 = pack_p8(s0, s1, lp1);
#pragma unroll
    for (int ds = 0; ds < 4; ++ds)
      oacc1[ds] = __builtin_amdgcn_mfma_f32_16x16x32_bf16(pa1, vb[ds], oacc1[ds], 0, 0, 0);
  }

  // per-wave L: lanes c, c+16, c+32, c+48 hold disjoint-key partials for q=c
  lp0 += __shfl_xor(lp0, 16, 64); lp0 += __shfl_xor(lp0, 32, 64);
  lp1 += __shfl_xor(lp1, 16, 64); lp1 += __shfl_xor(lp1, 32, 64);

  // O C-layout: oaccX[ds] reg r = O[q=quad*4+r][d=ds*16+c]; reduce sp in LDS
#pragma unroll
  for (int h = 0; h < 2; ++h) {
    __syncthreads();
    const f32x4* oa = h ? oacc1 : oacc0;
#pragma unroll
    for (int ds = 0; ds < 4; ++ds)
#pragma unroll
      for (int r = 0; r < 4; ++r)
        obuf[sp][quad * 4 + r][ds * 16 + c] = oa[ds][r];
    if (quad == 0) lbuf[sp][c] = h ? lp1 : lp0;
    __syncthreads();

    int q = tid >> 4, d0 = (tid & 15) * 4;
    f32x4 a = *(const f32x4*)&obuf[0][q][d0];
    a += *(const f32x4*)&obuf[1][q][d0];
    a += *(const f32x4*)&obuf[2][q][d0];
    a += *(const f32x4*)&obuf[3][q][d0];
    float l = lbuf[0][q] + lbuf[1][q] + lbuf[2][q] + lbuf[3][q];
    int hq = hp + 2 * h;
    union { uint32_t u[2]; } wv;
    wv.u[0] = pk2(a[0], a[1]);
    wv.u[1] = pk2(a[2], a[3]);
    *(uint2*)&Opart[(size_t)((z * 4 + kg) * N_PTS + n0 + q) * 256 + hq * 64 + d0] =
        *(uint2*)wv.u;
    if ((tid & 15) == 0)
      Lpart[((z * 4 + kg) * 4 + hq) * N_PTS + n0 + q] = l;
  }
}

// ---- final: out = sum_kg w(kg,hq) * (sum_z O) / (sum_z L), cast per detected dtype ----
__global__ void k_out(const ushort* __restrict__ Opart, const float* __restrict__ Lpart,
                      const void* __restrict__ x, void* __restrict__ out) {
  __shared__ int shflag;
  int isf32 = detect_f32((const ushort*)x, &shflag);
  int idx = blockIdx.x * 256 + threadIdx.x;
  int n = idx >> 8, o = idx & 255, hq = o >> 6;
  float acc = 0.f;
#pragma unroll
  for (int kg = 0; kg < 4; ++kg) {
    float num = bf2f(Opart[(size_t)((0 + kg) * N_PTS + n) * 256 + o]) +
                bf2f(Opart[(size_t)((4 + kg) * N_PTS + n) * 256 + o]);
    float l = Lpart[((0 + kg) * 4 + hq) * N_PTS + n] +
              Lpart[((4 + kg) * 4 + hq) * N_PTS + n];
    float w = (kg == ((hq + 2) & 3)) ? 2.f : 1.f;
    acc += w * num / l;
  }
  if (isf32) ((float*)out)[idx] = acc;
  else       ((ushort*)out)[idx] = f2bf(acc);
}

extern "C" void kernel_launch(void* const* d_in, const int* in_sizes, int n_in,
                              void* d_out, int out_size, void* d_ws, size_t ws_size,
                              hipStream_t stream) {
  char* ws = (char*)d_ws;
  ushort* Xc    = (ushort*)(ws + OFF_XC);
  ushort* WT    = (ushort*)(ws + OFF_WT);
  ushort* bias3 = (ushort*)(ws + OFF_BIAS);
  ushort* VhT   = (ushort*)(ws + OFF_VHT);
  ushort* Qh    = (ushort*)(ws + OFF_QH);
  ushort* Kh    = (ushort*)(ws + OFF_KH);
  ushort* Kf    = (ushort*)(ws + OFF_KF);
  ushort* Vf    = (ushort*)(ws + OFF_VF);
  ushort* Opart = (ushort*)(ws + OFF_OP);
  float*  Lpart = (float*)(ws + OFF_LP);

  k_prep<<<593, 256, 0, stream>>>(d_in[0], d_in[1], d_in[2], d_in[3],
                                  d_in[4], d_in[5], d_in[6], ws);
  k_proj<<<dim3(100, 1, 3), 256, 0, stream>>>(Xc, WT, bias3, Qh, Kh, VhT);
  k_frag<<<400, 256, 0, stream>>>(Kh, VhT, Kf, Vf);
  k_attn<<<dim3(100, 8, 2), 256, 0, stream>>>(Qh, Kf, Vf, Opart, Lpart);
  k_out<<<1600, 256, 0, stream>>>(Opart, Lpart, d_in[0], d_out);
}